// Round 11
// baseline (883.215 us; speedup 1.0000x reference)
//
#include <hip/hip_runtime.h>
#include <hip/hip_bf16.h>

typedef __hip_bfloat16 bf16;
typedef unsigned short ushort_t;
typedef unsigned int uint_t;
typedef __attribute__((ext_vector_type(8))) short short8;
typedef __attribute__((ext_vector_type(4))) float floatx4;

__device__ __forceinline__ float b2f(bf16 x) { return __bfloat162float(x); }
__device__ __forceinline__ ushort_t f2us(float f) { bf16 h = __float2bfloat16(f); return *(ushort_t*)&h; }
__device__ __forceinline__ float us2f(ushort_t u) { return __uint_as_float(((uint_t)u) << 16); }

constexpr int Bc = 4, Tc = 1024, Dc = 512, Hc = 8, HDc = 64;
constexpr int LCc = 128, MPc = 192;
constexpr float EPSc = 1e-4f;
constexpr int NBT = Bc * Tc;
constexpr long NE = (long)NBT * Dc;
constexpr float NEGB = -1e30f;
constexpr int PSTRIDE = 8704;   // bytes per attention partial: 4096 bf16 C + 64 f32 m + 64 f32 l
constexpr int QSTR = 768;       // fused qkv row stride: q 0..511 | K 512..639 | (V in vt)

__device__ __forceinline__ float wload(const void* p, long i, int f32) {
  return f32 ? ((const float*)p)[i] : b2f(((const bf16*)p)[i]);
}

// counted vmcnt wait (T4)
template<int N> __device__ __forceinline__ void vmwait() {
  if constexpr (N == 0)      asm volatile("s_waitcnt vmcnt(0)" ::: "memory");
  else if constexpr (N == 4) asm volatile("s_waitcnt vmcnt(4)" ::: "memory");
  else if constexpr (N == 6) asm volatile("s_waitcnt vmcnt(6)" ::: "memory");
  else if constexpr (N == 8) asm volatile("s_waitcnt vmcnt(8)" ::: "memory");
  else static_assert(N == 0, "unsupported vmcnt literal");
}

// async global->LDS staging of a ROWSx64 bf16 tile with XOR swizzle (T21 source-perm).
__device__ __forceinline__ void stage_swz(const ushort_t* __restrict__ G, int rowStride,
                                          int rowBase, int k0, ushort_t* L, int nChunk, int t) {
#pragma unroll
  for (int i = t; i < nChunk; i += 256) {
    int r = i >> 3;
    int cs = (i & 7) ^ (r & 7);
    const ushort_t* gp = G + (long)(rowBase + r) * rowStride + k0 + cs * 8;
    __builtin_amdgcn_global_load_lds(
        (const __attribute__((address_space(1))) void*)gp,
        (__attribute__((address_space(3))) void*)&L[(i & ~63) * 8], 16, 0, 0);
  }
}

// ---------------- dtype detector ----------------
__global__ void k_detect(const void* __restrict__ x, int* __restrict__ flag) {
  __shared__ int s[256];
  int t = threadIdx.x;
  const unsigned short* u = (const unsigned short*)x;
  int bad = 0;
  for (int j = t; j < 2048; j += 256) {
    int e = (u[j] >> 7) & 0xFF;
    if (e == 0xFF || e > 0x8F || (e != 0 && e < 0x6F)) bad++;
  }
  s[t] = bad;
  __syncthreads();
  for (int off = 128; off > 0; off >>= 1) { if (t < off) s[t] += s[t + off]; __syncthreads(); }
  if (t == 0) flag[0] = (s[0] > 16) ? 1 : 0;
}

__global__ void k_in(const void* __restrict__ in, float* __restrict__ out, int n,
                     const int* __restrict__ flag) {
  int i = blockIdx.x * 256 + threadIdx.x;
  if (i < n) out[i] = wload(in, i, flag[0]);
}
__global__ void k_out(const float* __restrict__ in, void* __restrict__ out, int n,
                      const int* __restrict__ flag) {
  int i = blockIdx.x * 256 + threadIdx.x;
  if (i >= n) return;
  if (flag[0]) ((float*)out)[i] = in[i];
  else         ((bf16*)out)[i] = __float2bfloat16(in[i]);
}

// ---------------- one-shot weight conversion ----------------
__global__ void k_w2all(const void* wq, const void* wk, const void* wv, const void* wo,
                        const void* rel, const void* pw1, const void* dwv, const void* pw2,
                        const void* w1, const void* w2,
                        ushort_t* __restrict__ wbf, const int* __restrict__ flag) {
  int f32 = flag[0];
  long i = (long)blockIdx.x * 256 + threadIdx.x;
  if (i >= 12175104L) return;
  float v;
  if (i < 1572864) {
    long l = i / 393216, rem = i - l * 393216;
    int r = (int)(rem >> 9), c = (int)(rem & 511);
    if (r < 512)      v = 0.125f * wload(wq, l * 262144 + (long)r * 512 + c, f32);
    else if (r < 640) v = wload(wk, l * 65536 + (long)(r - 512) * 512 + c, f32);
    else              v = wload(wv, l * 65536 + (long)(r - 640) * 512 + c, f32);
  } else if (i < 2621440) {
    v = wload(wo, i - 1572864, f32);
  } else if (i < 2719488) {
    v = wload(rel, i - 2621440, f32);
  } else if (i < 4816640) {
    v = wload(pw1, i - 2719488, f32);
  } else if (i < 4835072) {
    long r2 = i - 4816640;
    long l = r2 / 4608, rem = r2 - l * 4608;
    int j = (int)(rem >> 9), d = (int)(rem & 511);
    v = wload(dwv, l * 4608 + (long)d * 9 + j, f32);
  } else if (i < 5883648) {
    v = wload(pw2, i - 4835072, f32);
  } else if (i < 10077952) {
    v = wload(w1, i - 5883648, f32);
  } else {
    v = wload(w2, i - 10077952, f32);
  }
  wbf[i] = f2us(v);
}

// ---------------- LayerNorm: wave-per-row, pure shuffle reduce, ZERO barriers ----------------
__global__ __launch_bounds__(256) void k_ln(const float* __restrict__ x,
    const void* __restrict__ w, const void* __restrict__ bb, long woff,
    float* __restrict__ o, ushort_t* __restrict__ oA, const int* __restrict__ flag) {
  int f32 = flag[0];
  int t = threadIdx.x;
  int lane = t & 63;
  int row = blockIdx.x * 4 + (t >> 6);
  const float4* xr = (const float4*)(x + (long)row * Dc);
  float4 va = xr[lane * 2], vb = xr[lane * 2 + 1];
  float s = va.x + va.y + va.z + va.w + vb.x + vb.y + vb.z + vb.w;
#pragma unroll
  for (int o2 = 1; o2 < 64; o2 <<= 1) s += __shfl_xor(s, o2, 64);
  float mean = s * (1.0f / Dc);
  float d[8] = {va.x - mean, va.y - mean, va.z - mean, va.w - mean,
                vb.x - mean, vb.y - mean, vb.z - mean, vb.w - mean};
  float s2 = 0.f;
#pragma unroll
  for (int e = 0; e < 8; ++e) s2 += d[e] * d[e];
#pragma unroll
  for (int o2 = 1; o2 < 64; o2 <<= 1) s2 += __shfl_xor(s2, o2, 64);
  float inv = 1.0f / sqrtf(s2 * (1.0f / Dc) + EPSc);
  float v[8];
#pragma unroll
  for (int e = 0; e < 8; ++e)
    v[e] = d[e] * inv * wload(w, woff + lane * 8 + e, f32) + wload(bb, woff + lane * 8 + e, f32);
  float4 o0 = {v[0], v[1], v[2], v[3]}, o1 = {v[4], v[5], v[6], v[7]};
  float4* orow = (float4*)(o + (long)row * Dc);
  orow[lane * 2] = o0; orow[lane * 2 + 1] = o1;
  uint4 pk;
  pk.x = (uint_t)f2us(v[0]) | ((uint_t)f2us(v[1]) << 16);
  pk.y = (uint_t)f2us(v[2]) | ((uint_t)f2us(v[3]) << 16);
  pk.z = (uint_t)f2us(v[4]) | ((uint_t)f2us(v[5]) << 16);
  pk.w = (uint_t)f2us(v[6]) | ((uint_t)f2us(v[7]) << 16);
  *(uint4*)&oA[(long)row * Dc + lane * 8] = pk;
}

// ---------------- bf16 MFMA GEMM, counted-vmcnt 2-phase pipeline (T3-min + T4) --------------
// QKV=1, n0>=640: V projection. Epilogue transposes the 64x64 block through LDS (packed,
// aligned uint2 stores; pitch 68 => byte pitch 136 = 8*17 keeps 4-token groups 8B-aligned),
// then stores COALESCED token-runs into tiled vt[b][ktile][128 d][64 tok] (dense 8KB/g-half).
template<int BM, int BN, bool OBF, int QKV>
__global__ __launch_bounds__(256) void k_gemm_b(const ushort_t* __restrict__ A, int lda,
    const ushort_t* __restrict__ W, void* __restrict__ C, int ldc,
    const float* __restrict__ addend, float alpha, int K, ushort_t* __restrict__ vtw) {
  constexpr int WGM = BM / 64;
  constexpr int WGN = 4 / WGM;
  constexpr int WN = BN / WGN;
  constexpr int NJ = WN / 16;
  constexpr int LPI = (BM * 8 + BN * 8) / 256;
  __shared__ ushort_t As[2][BM * 64];
  __shared__ ushort_t Ws[2][BN * 64];
  int t = threadIdx.x;
  int m0 = blockIdx.y * BM, n0 = blockIdx.x * BN;
  int lane = t & 63, wv = t >> 6;
  int l15 = lane & 15, quad = lane >> 4;
  int wrow = (WGM == 2) ? (wv >> 1) * 64 : 0;
  int wcol = (WGM == 2) ? (wv & 1) * WN : wv * WN;
  floatx4 acc[4][NJ];
#pragma unroll
  for (int i = 0; i < 4; ++i)
#pragma unroll
    for (int j = 0; j < NJ; ++j) acc[i][j] = 0;
  stage_swz(A, lda, m0, 0, As[0], BM * 8, t);
  stage_swz(W, K,  n0, 0, Ws[0], BN * 8, t);
  int cur = 0;
  for (int k0 = 0; k0 < K; k0 += 64) {
    int nk = k0 + 64;
    if (nk < K) {
      stage_swz(A, lda, m0, nk, As[cur ^ 1], BM * 8, t);
      stage_swz(W, K,  n0, nk, Ws[cur ^ 1], BN * 8, t);
      vmwait<LPI>();
    } else {
      vmwait<0>();
    }
    __builtin_amdgcn_s_barrier();
    __builtin_amdgcn_sched_barrier(0);
    const ushort_t* Asc = As[cur];
    const ushort_t* Wsc = Ws[cur];
#pragma unroll
    for (int half = 0; half < 2; ++half) {
      int sw = ((half * 4 + quad) ^ (l15 & 7)) << 3;
      short8 af[4], bfr[NJ];
#pragma unroll
      for (int i = 0; i < 4; ++i) af[i] = *(short8*)&Asc[(wrow + i * 16 + l15) * 64 + sw];
#pragma unroll
      for (int j = 0; j < NJ; ++j) bfr[j] = *(short8*)&Wsc[(wcol + j * 16 + l15) * 64 + sw];
#pragma unroll
      for (int i = 0; i < 4; ++i)
#pragma unroll
        for (int j = 0; j < NJ; ++j)
          acc[i][j] = __builtin_amdgcn_mfma_f32_16x16x32_bf16(af[i], bfr[j], acc[i][j], 0, 0, 0);
    }
    __builtin_amdgcn_s_barrier();
    cur ^= 1;
  }
  if (QKV && n0 >= 640) {
    // V^T via LDS: Ts[d][tok], pitch 68 (byte pitch 136, 8B-aligned 4-token groups)
    ushort_t* Ts = As[0];               // 64*68 = 4352 ushort <= 8192 available
#pragma unroll
    for (int i = 0; i < 4; ++i) {
      int d = wcol + l15;
      int tok = i * 16 + quad * 4;
      uint2 pk;
      pk.x = (uint_t)f2us(acc[i][0][0]) | ((uint_t)f2us(acc[i][0][1]) << 16);
      pk.y = (uint_t)f2us(acc[i][0][2]) | ((uint_t)f2us(acc[i][0][3]) << 16);
      *(uint2*)&Ts[d * 68 + tok] = pk;
    }
    __builtin_amdgcn_s_barrier();
    // coalesced store: thread t -> d = t>>2 (local), 16-token run (t&3)*16
    {
      int dl = t >> 2, tc = (t & 3) * 16;
      uint4 a = *(uint4*)&Ts[dl * 68 + tc];
      uint4 b2 = *(uint4*)&Ts[dl * 68 + tc + 8];
      long off = (((long)(m0 >> 10) * 16 + ((m0 >> 6) & 15)) * 128 + (n0 - 640 + dl)) * 64 + tc;
      *(uint4*)(vtw + off) = a;
      *(uint4*)(vtw + off + 8) = b2;
    }
    return;
  }
#pragma unroll
  for (int i = 0; i < 4; ++i) {
#pragma unroll
    for (int j = 0; j < NJ; ++j) {
#pragma unroll
      for (int rg = 0; rg < 4; ++rg) {
        int m = m0 + wrow + i * 16 + quad * 4 + rg;
        int n = n0 + wcol + j * 16 + l15;
        float v = alpha * acc[i][j][rg];
        if (addend) v += addend[(long)m * ldc + n];
        if (OBF) ((ushort_t*)C)[(long)m * ldc + n] = f2us(v);
        else     ((float*)C)[(long)m * ldc + n] = v;
      }
    }
  }
}

// ---------------- gated GEMM (counted-vmcnt pipeline): C = gate(A@Wa^T, A@Wg^T) -------------
template<int MODE>
__global__ __launch_bounds__(256) void k_gemm_gate(const ushort_t* __restrict__ A, int lda,
    const ushort_t* __restrict__ Wa, const ushort_t* __restrict__ Wg,
    ushort_t* __restrict__ C, int ldc, int K) {
  __shared__ ushort_t As[2][64 * 64];
  __shared__ ushort_t Wsa[2][64 * 64];
  __shared__ ushort_t Wsg[2][64 * 64];
  int t = threadIdx.x;
  int m0 = blockIdx.y * 64, n0 = blockIdx.x * 64;
  int lane = t & 63, wv = t >> 6;
  int l15 = lane & 15, quad = lane >> 4;
  int wcol = wv * 16;
  floatx4 acca[4], accg[4];
#pragma unroll
  for (int i = 0; i < 4; ++i) { acca[i] = 0; accg[i] = 0; }
  stage_swz(A, lda, m0, 0, As[0], 512, t);
  stage_swz(Wa, K, n0, 0, Wsa[0], 512, t);
  stage_swz(Wg, K, n0, 0, Wsg[0], 512, t);
  int cur = 0;
  for (int k0 = 0; k0 < K; k0 += 64) {
    int nk = k0 + 64;
    if (nk < K) {
      stage_swz(A, lda, m0, nk, As[cur ^ 1], 512, t);
      stage_swz(Wa, K, n0, nk, Wsa[cur ^ 1], 512, t);
      stage_swz(Wg, K, n0, nk, Wsg[cur ^ 1], 512, t);
      vmwait<6>();
    } else {
      vmwait<0>();
    }
    __builtin_amdgcn_s_barrier();
    __builtin_amdgcn_sched_barrier(0);
    const ushort_t* Asc = As[cur];
    const ushort_t* Wac = Wsa[cur];
    const ushort_t* Wgc = Wsg[cur];
#pragma unroll
    for (int half = 0; half < 2; ++half) {
      int sw = ((half * 4 + quad) ^ (l15 & 7)) << 3;
      short8 af[4], ba, bg;
#pragma unroll
      for (int i = 0; i < 4; ++i) af[i] = *(short8*)&Asc[(i * 16 + l15) * 64 + sw];
      ba = *(short8*)&Wac[(wcol + l15) * 64 + sw];
      bg = *(short8*)&Wgc[(wcol + l15) * 64 + sw];
#pragma unroll
      for (int i = 0; i < 4; ++i) {
        acca[i] = __builtin_amdgcn_mfma_f32_16x16x32_bf16(af[i], ba, acca[i], 0, 0, 0);
        accg[i] = __builtin_amdgcn_mfma_f32_16x16x32_bf16(af[i], bg, accg[i], 0, 0, 0);
      }
    }
    __builtin_amdgcn_s_barrier();
    cur ^= 1;
  }
#pragma unroll
  for (int i = 0; i < 4; ++i) {
#pragma unroll
    for (int rg = 0; rg < 4; ++rg) {
      int m = m0 + i * 16 + quad * 4 + rg;
      int n = n0 + wcol + l15;
      float a = acca[i][rg], g = accg[i][rg];
      float v;
      if (MODE == 0) v = a * (1.0f / (1.0f + __expf(-g)));
      else           v = (a / (1.0f + __expf(-a))) * g;
      C[(long)m * ldc + n] = f2us(v);
    }
  }
}

// ---------------- flash attention: swapped-QK + grid split-K; V tiled-transposed in vt -------
// qkv: [4096][768] (q 0..511, K 512..639); vt: [b][ktile][128 d][64 tok] (dense 8KB per g-half).
__global__ __launch_bounds__(256, 3) void k_attn(const ushort_t* __restrict__ qkv,
    const ushort_t* __restrict__ vt,
    const ushort_t* __restrict__ relL, const int* __restrict__ alen,
    ushort_t* __restrict__ out, char* __restrict__ part) {
  int bx = blockIdx.x;
  int h = blockIdx.y, b = blockIdx.z;
  int len = alen[b];
  int inv, qt, grp;
  if (bx < 16) { inv = 0; qt = bx; grp = 0; }
  else         { inv = 1; qt = (bx - 16) & 15; grp = (bx - 16) >> 4; }
  int q0 = qt * 64;
  if (inv) { if (q0 + 64 <= len) return; }
  else     { if (q0 >= len) return; }
  int nvalid = min(len - q0, 64);
  int g = h >> 2;
  __shared__ __align__(16) ushort_t B2t[8704];
  __shared__ __align__(16) ushort_t Ks[64 * 64];
  __shared__ __align__(16) ushort_t Vt[64 * 64];
  __shared__ __align__(16) ushort_t Ps[64 * 64];
  __shared__ __align__(16) float fML[128];
  int t = threadIdx.x;
  int lane = t & 63, w = t >> 6;
  int l15 = lane & 15, quad = lane >> 4;
  int qw = w * 16;
  const ushort_t* qrow = qkv + ((long)(b * Tc + q0 + qw + l15)) * QSTR + h * 64;
  short8 aq0 = *(const short8*)(qrow + quad * 8);
  short8 aq1 = *(const short8*)(qrow + 32 + quad * 8);
  const int koB = inv ? -128 : (q0 - 128);
  const int KSTEP = inv ? 4 : 1;
  const int nIt = inv ? ((grp < 2) ? 5 : 4) : 3;
  uint4 kr0, kr1, vr0, vr1;
  int kj = t >> 2, du = (t & 3) * 16, c0 = du >> 3;
  int vd = t >> 2, vc = (t & 3) * 2;
  auto LOADKV = [&](int kt2) {
    int ko0x = koB + kt2 * 64;
    if (ko0x >= 0) {
      long basek = ((long)(b * Tc + ko0x + kj)) * QSTR + 512 + g * 64 + du;
      kr0 = *(const uint4*)(qkv + basek);
      kr1 = *(const uint4*)(qkv + basek + 8);
      long basev = (((long)b * 16 + (ko0x >> 6)) * 128 + g * 64 + vd) * 64 + (t & 3) * 16;
      vr0 = *(const uint4*)(vt + basev);
      vr1 = *(const uint4*)(vt + basev + 8);
    } else {
      uint4 z = {0, 0, 0, 0};
      kr0 = z; kr1 = z; vr0 = z; vr1 = z;
    }
  };
  LOADKV(grp);
  float m_ = NEGB, l_ = 0.f;
  floatx4 acc[4];
#pragma unroll
  for (int j = 0; j < 4; ++j) acc[j] = 0;
  float rv_lo = 0.f, rv_hi = 0.f;
  if (inv) {
    int er = (l15 == 1) ? 382 : 0;
    short8 be0 = *(const short8*)(relL + (long)er * 64 + quad * 8);
    short8 be1 = *(const short8*)(relL + (long)er * 64 + 32 + quad * 8);
    floatx4 ec = {0.f, 0.f, 0.f, 0.f};
    ec = __builtin_amdgcn_mfma_f32_16x16x32_bf16(be0, aq0, ec, 0, 0, 0);
    ec = __builtin_amdgcn_mfma_f32_16x16x32_bf16(be1, aq1, ec, 0, 0, 0);
    rv_lo = __shfl(ec[0], l15, 64);
    rv_hi = __shfl(ec[1], l15, 64);
  }
  int sw7 = l15 & 7;
  for (int it = 0; it < nIt; ++it) {
    int kt = inv ? (grp + it * KSTEP) : it;
    int ko0 = koB + kt * 64;
    int t0 = q0 - ko0 + 191;
    bool far_hi = (q0 - ko0 - 63) >= 191;
    bool far_lo = (q0 + 63 - ko0) <= -191;
    bool near = !far_hi && !far_lo;
    int cb = min(max(t0 - 63, 0), 255);
    __syncthreads();   // A
    {
      *(uint4*)&Ks[kj * 64 + ((c0 ^ (kj & 7)) << 3)] = kr0;
      *(uint4*)&Ks[kj * 64 + (((c0 + 1) ^ (kj & 7)) << 3)] = kr1;
      *(uint4*)&Vt[vd * 64 + ((vc ^ (vd & 7)) << 3)] = vr0;
      *(uint4*)&Vt[vd * 64 + (((vc + 1) ^ (vd & 7)) << 3)] = vr1;
    }
    if (near) {
      __builtin_amdgcn_s_setprio(1);
#pragma unroll
      for (int p = 0; p < 2; ++p) {
        short8 rw0[4], rw1[4];
#pragma unroll
        for (int j = 0; j < 4; ++j) {
          long wr = cb + (p * 4 + j) * 16 + l15;
          rw0[j] = *(const short8*)(relL + wr * 64 + quad * 8);
          rw1[j] = *(const short8*)(relL + wr * 64 + 32 + quad * 8);
        }
#pragma unroll
        for (int j = 0; j < 4; ++j) {
          floatx4 z = {0.f, 0.f, 0.f, 0.f};
          z = __builtin_amdgcn_mfma_f32_16x16x32_bf16(rw0[j], aq0, z, 0, 0, 0);
          z = __builtin_amdgcn_mfma_f32_16x16x32_bf16(rw1[j], aq1, z, 0, 0, 0);
#pragma unroll
          for (int rg = 0; rg < 4; ++rg) {
            int cpr = (p * 4 + j) * 16 + quad * 4 + rg;
            B2t[cpr * 68 + qw + l15] = f2us(z[rg]);
          }
        }
      }
      __builtin_amdgcn_s_setprio(0);
    }
    __syncthreads();   // B
    if (it + 1 < nIt) LOADKV(kt + KSTEP);
    floatx4 s[4];
    __builtin_amdgcn_s_setprio(1);
#pragma unroll
    for (int nt = 0; nt < 4; ++nt) {
      short8 ak0 = *(short8*)&Ks[(nt * 16 + l15) * 64 + ((quad ^ sw7) << 3)];
      short8 ak1 = *(short8*)&Ks[(nt * 16 + l15) * 64 + (((4 + quad) ^ sw7) << 3)];
      floatx4 z = {0.f, 0.f, 0.f, 0.f};
      z = __builtin_amdgcn_mfma_f32_16x16x32_bf16(ak0, aq0, z, 0, 0, 0);
      z = __builtin_amdgcn_mfma_f32_16x16x32_bf16(ak1, aq1, z, 0, 0, 0);
      s[nt] = z;
    }
    __builtin_amdgcn_s_setprio(0);
    if (near) {
#pragma unroll
      for (int nt = 0; nt < 4; ++nt)
#pragma unroll
        for (int rg = 0; rg < 4; ++rg) {
          int c = t0 + qw + l15 - (nt * 16 + quad * 4 + rg);
          c = min(max(c, 0), 382);
          s[nt][rg] += us2f(B2t[(c - cb) * 68 + qw + l15]);
        }
    } else {
      float rv = far_hi ? rv_hi : rv_lo;
#pragma unroll
      for (int nt = 0; nt < 4; ++nt)
#pragma unroll
        for (int rg = 0; rg < 4; ++rg) s[nt][rg] += rv;
    }
    if (!inv) {
#pragma unroll
      for (int nt = 0; nt < 4; ++nt)
#pragma unroll
        for (int rg = 0; rg < 4; ++rg) {
          int ko = ko0 + nt * 16 + quad * 4 + rg;
          if (ko >= len) s[nt][rg] = NEGB;
        }
    }
    float mx = s[0][0];
#pragma unroll
    for (int nt = 0; nt < 4; ++nt)
#pragma unroll
      for (int rg = 0; rg < 4; ++rg) mx = fmaxf(mx, s[nt][rg]);
    mx = fmaxf(mx, __shfl_xor(mx, 16, 64));
    mx = fmaxf(mx, __shfl_xor(mx, 32, 64));
    float mn = fmaxf(m_, mx);
    float al = __expf(m_ - mn);
    float ps = 0.f;
#pragma unroll
    for (int nt = 0; nt < 4; ++nt)
#pragma unroll
      for (int rg = 0; rg < 4; ++rg) {
        float p = __expf(s[nt][rg] - mn);
        s[nt][rg] = p;
        ps += p;
      }
    ps += __shfl_xor(ps, 16, 64);
    ps += __shfl_xor(ps, 32, 64);
    l_ = l_ * al + ps;
    m_ = mn;
    if (quad == 0) fML[qw + l15] = al;
#pragma unroll
    for (int nt = 0; nt < 4; ++nt)
#pragma unroll
      for (int pr = 0; pr < 2; ++pr) {
        uint_t pk = (uint_t)f2us(s[nt][2 * pr]) | ((uint_t)f2us(s[nt][2 * pr + 1]) << 16);
        int e = nt * 16 + quad * 4 + pr * 2;
        *(uint_t*)&Ps[(qw + l15) * 64 + (((e >> 3) ^ sw7) << 3) + (e & 7)] = pk;
      }
    floatx4 av = *(floatx4*)&fML[qw + quad * 4];
#pragma unroll
    for (int j = 0; j < 4; ++j)
#pragma unroll
      for (int rg = 0; rg < 4; ++rg) acc[j][rg] *= av[rg];
    short8 ap0 = *(short8*)&Ps[(qw + l15) * 64 + ((quad ^ sw7) << 3)];
    short8 ap1 = *(short8*)&Ps[(qw + l15) * 64 + (((4 + quad) ^ sw7) << 3)];
    __builtin_amdgcn_s_setprio(1);
#pragma unroll
    for (int j = 0; j < 4; ++j) {
      int rd = j * 16 + l15;
      short8 bv0 = *(short8*)&Vt[rd * 64 + ((quad ^ (rd & 7)) << 3)];
      short8 bv1 = *(short8*)&Vt[rd * 64 + (((4 + quad) ^ (rd & 7)) << 3)];
      acc[j] = __builtin_amdgcn_mfma_f32_16x16x32_bf16(ap0, bv0, acc[j], 0, 0, 0);
      acc[j] = __builtin_amdgcn_mfma_f32_16x16x32_bf16(ap1, bv1, acc[j], 0, 0, 0);
    }
    __builtin_amdgcn_s_setprio(0);
  }
  if (inv) {
    char* pp = part + (long)((((b * 8 + h) * 16 + qt) * 4 + grp)) * PSTRIDE;
    ushort_t* Cp = (ushort_t*)pp;
    float* mp = (float*)(pp + 8192);
#pragma unroll
    for (int j = 0; j < 4; ++j)
#pragma unroll
      for (int rg = 0; rg < 4; ++rg)
        Cp[(qw + quad * 4 + rg) * 64 + j * 16 + l15] = f2us(acc[j][rg]);
    if (quad == 0) { mp[qw + l15] = m_; mp[64 + qw + l15] = l_; }
  } else {
    if (quad == 0) fML[64 + qw + l15] = l_;
    __syncthreads();
    floatx4 lv = *(floatx4*)&fML[64 + qw + quad * 4];
#pragma unroll
    for (int rg = 0; rg < 4; ++rg) {
      int R = qw + quad * 4 + rg;
      if (R < nvalid) {
        float invL = 1.0f / lv[rg];
#pragma unroll
        for (int j = 0; j < 4; ++j)
          out[((long)(b * Tc + q0 + R)) * Dc + h * 64 + j * 16 + l15] = f2us(acc[j][rg] * invL);
      }
    }
  }
}

// ---------------- exact split-K combine for inv partials ----------------
__global__ __launch_bounds__(256) void k_comb(const char* __restrict__ part,
    const int* __restrict__ alen, ushort_t* __restrict__ out) {
  int qt = blockIdx.x, h = blockIdx.y, b = blockIdx.z;
  int len = alen[b];
  int q0 = qt * 64;
  if (q0 + 64 <= len) return;
  int nskip = max(len - q0, 0);
  int t = threadIdx.x;
  int d = t & 63, r0 = (t >> 6) * 16;
  const char* pb = part + (long)(((b * 8 + h) * 16 + qt) * 4) * PSTRIDE;
#pragma unroll 4
  for (int i = 0; i < 16; ++i) {
    int r = r0 + i;
    if (r < nskip) continue;
    float mg[4], lg[4], M = NEGB;
#pragma unroll
    for (int g2 = 0; g2 < 4; ++g2) {
      const float* mp = (const float*)(pb + g2 * PSTRIDE + 8192);
      mg[g2] = mp[r];
      lg[g2] = mp[64 + r];
      M = fmaxf(M, mg[g2]);
    }
    float L = 0.f, wgt[4];
#pragma unroll
    for (int g2 = 0; g2 < 4; ++g2) { wgt[g2] = __expf(mg[g2] - M); L += lg[g2] * wgt[g2]; }
    float v = 0.f;
#pragma unroll
    for (int g2 = 0; g2 < 4; ++g2)
      v += us2f(((const ushort_t*)(pb + g2 * PSTRIDE))[r * 64 + d]) * wgt[g2];
    out[((long)(b * Tc + q0 + r)) * Dc + h * 64 + d] = f2us(v / L);
  }
}

// ---------------- depthwise conv (gated input [4096][512], short8) ----------------
__global__ void k_dwconv(const ushort_t* __restrict__ in, const ushort_t* __restrict__ dwT,
                         ushort_t* __restrict__ out, int n8) {
  int i = blockIdx.x * 256 + threadIdx.x;
  if (i >= n8) return;
  int row = i >> 6;            // 0..4095
  int d8 = (i & 63) << 3;
  int t = row & (Tc - 1);
  int b = row >> 10;
  float acc[8] = {0, 0, 0, 0, 0, 0, 0, 0};
#pragma unroll
  for (int j = 0; j < 9; ++j) {
    int tt = t + j - 4;
    if (tt < 0 || tt >= Tc) continue;
    short8 vv = *(const short8*)&in[((long)(b * Tc + tt) << 9) + d8];
    short8 dv = *(const short8*)&dwT[j * 512 + d8];
#pragma unroll
    for (int e = 0; e < 8; ++e)
      acc[e] += us2f((ushort_t)vv[e]) * us2f((ushort_t)dv[e]);
  }
  short8 o8;
#pragma unroll
  for (int e = 0; e < 8; ++e)
    o8[e] = (short)f2us(acc[e] * (1.0f / (1.0f + __expf(-acc[e]))));
  *(short8*)&out[(long)row * 512 + d8] = o8;
}

extern "C" void kernel_launch(void* const* d_in, const int* in_sizes, int n_in,
                              void* d_out, int out_size, void* d_ws, size_t ws_size,
                              hipStream_t stream) {
  const void* x_in = d_in[0];
  const int*  alen = (const int*)d_in[1];
  const void* ln1w = d_in[2];
  const void* ln1b = d_in[3];
  const void* wq   = d_in[4];
  const void* wk   = d_in[5];
  const void* wv   = d_in[6];
  const void* wo   = d_in[7];
  const void* rel  = d_in[8];
  const void* ln2w = d_in[9];
  const void* ln2b = d_in[10];
  const void* pw1  = d_in[11];
  const void* dwv  = d_in[12];
  const void* pw2  = d_in[13];
  const void* ln3w = d_in[14];
  const void* ln3b = d_in[15];
  const void* w1   = d_in[16];
  const void* w2   = d_in[17];

  // ---- workspace layout (bytes) ----
  char* base = (char*)d_ws;
  int*      flag = (int*)base;                       // 256
  float*    xf   = (float*)(base + 256);             // 8 MB f32 residual
  float*    lnb  = (float*)(base + 256 + 8388608);   // 8 MB f32 LN out (addend)
  ushort_t* lnA  = (ushort_t*)(base + 16777472);     // 4 MB bf16 LN out (GEMM A)
  ushort_t* wbf  = (ushort_t*)(base + 20971776);     // bf16 weights
  char*     U    = base + 45321984;                  // phase union
  // attn phase
  ushort_t* qkv = (ushort_t*)U;                      // 6 MB fused q|K [4096][768]
  ushort_t* ab  = (ushort_t*)(U + 6291456);          // 4 MB
  ushort_t* vtb = (ushort_t*)(U + 10485760);         // 1 MB V transposed [4][16][128][64]
  char*     partA = U + 11534336;                    // 17.8 MB attn partials
  // conv/ffn phase
  ushort_t* big = (ushort_t*)U;                      // up to 8 MB (gated outputs)
  ushort_t* cb  = (ushort_t*)(U + 16777216);         // 4 MB
  size_t REQ = 45321984 + 16777216 + 4194304;
  size_t REQ2 = 45321984 + 35651584;
  if (REQ2 > REQ) REQ = REQ2;
  if (ws_size < REQ) return;

  // bf16 weight table offsets (elements)
  ushort_t* qkvB  = wbf + 0;         // [L][768][512] (wq pre-scaled by 0.125)
  ushort_t* woB   = wbf + 1572864;
  ushort_t* relB  = wbf + 2621440;
  ushort_t* pw1B  = wbf + 2719488;
  ushort_t* dwB   = wbf + 4816640;   // [L][9][512] transposed
  ushort_t* pw2B  = wbf + 4835072;
  ushort_t* w1B   = wbf + 5883648;
  ushort_t* w2B   = wbf + 10077952;

  k_detect<<<1, 256, 0, stream>>>(x_in, flag);
  k_in<<<(int)((NE + 255) / 256), 256, 0, stream>>>(x_in, xf, (int)NE, flag);
  k_w2all<<<47559, 256, 0, stream>>>(wq, wk, wv, wo, rel, pw1, dwv, pw2, w1, w2, wbf, flag);

  for (int i = 0; i < 4; ++i) {
    long oLN = (long)i * Dc;
    // ---- attention ----
    k_ln<<<NBT / 4, 256, 0, stream>>>(xf, ln1w, ln1b, oLN, lnb, lnA, flag);
    k_gemm_b<64, 64, true, 1><<<dim3(12, 64), 256, 0, stream>>>(lnA, Dc, qkvB + (long)i * 393216, qkv, QSTR, nullptr, 1.0f, 512, vtb);
    k_attn<<<dim3(80, 8, 4), 256, 0, stream>>>(qkv, vtb, relB + (long)i * 24512, alen, ab, partA);
    k_comb<<<dim3(16, 8, 4), 256, 0, stream>>>(partA, alen, ab);
    k_gemm_b<64, 64, false, 0><<<dim3(8, 64), 256, 0, stream>>>(ab, Dc, woB + (long)i * 262144, xf, Dc, lnb, 1.0f, 512, nullptr);

    // ---- conv ----
    k_ln<<<NBT / 4, 256, 0, stream>>>(xf, ln2w, ln2b, oLN, lnb, lnA, flag);
    k_gemm_gate<0><<<dim3(8, 64), 256, 0, stream>>>(lnA, Dc, pw1B + (long)i * 524288,
        pw1B + (long)i * 524288 + 262144, big, 512, 512);
    k_dwconv<<<NBT * 512 / 8 / 256, 256, 0, stream>>>(big, dwB + (long)i * 4608, cb, NBT * 512 / 8);
    k_gemm_b<64, 64, false, 0><<<dim3(8, 64), 256, 0, stream>>>(cb, Dc, pw2B + (long)i * 262144, xf, Dc, lnb, 1.0f, 512, nullptr);

    // ---- ffn ----
    k_ln<<<NBT / 4, 256, 0, stream>>>(xf, ln3w, ln3b, oLN, lnb, lnA, flag);
    k_gemm_gate<1><<<dim3(16, 64), 256, 0, stream>>>(lnA, Dc, w1B + (long)i * 1048576,
        w1B + (long)i * 1048576 + 524288, big, 1024, 512);
    k_gemm_b<64, 64, false, 0><<<dim3(8, 64), 256, 0, stream>>>(big, 1024, w2B + (long)i * 524288, xf, Dc, lnb, 1.0f, 1024, nullptr);
  }

  k_out<<<(int)((NE + 255) / 256), 256, 0, stream>>>(xf, d_out, (int)NE, flag);
}

// Round 12
// 854.928 us; speedup vs baseline: 1.0331x; 1.0331x over previous
//
#include <hip/hip_runtime.h>
#include <hip/hip_bf16.h>

typedef __hip_bfloat16 bf16;
typedef unsigned short ushort_t;
typedef unsigned int uint_t;
typedef __attribute__((ext_vector_type(8))) short short8;
typedef __attribute__((ext_vector_type(4))) float floatx4;

__device__ __forceinline__ float b2f(bf16 x) { return __bfloat162float(x); }
__device__ __forceinline__ ushort_t f2us(float f) { bf16 h = __float2bfloat16(f); return *(ushort_t*)&h; }
__device__ __forceinline__ float us2f(ushort_t u) { return __uint_as_float(((uint_t)u) << 16); }

constexpr int Bc = 4, Tc = 1024, Dc = 512, Hc = 8, HDc = 64;
constexpr int LCc = 128, MPc = 192;
constexpr float EPSc = 1e-4f;
constexpr int NBT = Bc * Tc;
constexpr long NE = (long)NBT * Dc;
constexpr float NEGB = -1e30f;
constexpr int PSTRIDE = 8704;   // bytes per attention partial: 4096 bf16 C + 64 f32 m + 64 f32 l
constexpr int QSTR = 768;       // fused qkv row stride: q 0..511 | K 512..639 | V 640..767

__device__ __forceinline__ float wload(const void* p, long i, int f32) {
  return f32 ? ((const float*)p)[i] : b2f(((const bf16*)p)[i]);
}

// counted vmcnt wait (T4): wait until at most N of this wave's vector-mem ops outstanding.
// NEVER vmcnt(0) inside the pipelined loop — that re-creates the barrier-drain stall.
template<int N> __device__ __forceinline__ void vmwait() {
  if constexpr (N == 0)       asm volatile("s_waitcnt vmcnt(0)" ::: "memory");
  else if constexpr (N == 4)  asm volatile("s_waitcnt vmcnt(4)" ::: "memory");
  else if constexpr (N == 6)  asm volatile("s_waitcnt vmcnt(6)" ::: "memory");
  else if constexpr (N == 8)  asm volatile("s_waitcnt vmcnt(8)" ::: "memory");
  else if constexpr (N == 12) asm volatile("s_waitcnt vmcnt(12)" ::: "memory");
  else static_assert(N == 0, "unsupported vmcnt literal");
}

// async global->LDS staging of a ROWSx64 bf16 tile with XOR swizzle (T21 source-perm).
__device__ __forceinline__ void stage_swz(const ushort_t* __restrict__ G, int rowStride,
                                          int rowBase, int k0, ushort_t* L, int nChunk, int t) {
#pragma unroll
  for (int i = t; i < nChunk; i += 256) {
    int r = i >> 3;
    int cs = (i & 7) ^ (r & 7);
    const ushort_t* gp = G + (long)(rowBase + r) * rowStride + k0 + cs * 8;
    __builtin_amdgcn_global_load_lds(
        (const __attribute__((address_space(1))) void*)gp,
        (__attribute__((address_space(3))) void*)&L[(i & ~63) * 8], 16, 0, 0);
  }
}

// ---------------- dtype detector ----------------
__global__ void k_detect(const void* __restrict__ x, int* __restrict__ flag) {
  __shared__ int s[256];
  int t = threadIdx.x;
  const unsigned short* u = (const unsigned short*)x;
  int bad = 0;
  for (int j = t; j < 2048; j += 256) {
    int e = (u[j] >> 7) & 0xFF;
    if (e == 0xFF || e > 0x8F || (e != 0 && e < 0x6F)) bad++;
  }
  s[t] = bad;
  __syncthreads();
  for (int off = 128; off > 0; off >>= 1) { if (t < off) s[t] += s[t + off]; __syncthreads(); }
  if (t == 0) flag[0] = (s[0] > 16) ? 1 : 0;
}

__global__ void k_in(const void* __restrict__ in, float* __restrict__ out, int n,
                     const int* __restrict__ flag) {
  int i = blockIdx.x * 256 + threadIdx.x;
  if (i < n) out[i] = wload(in, i, flag[0]);
}
__global__ void k_out(const float* __restrict__ in, void* __restrict__ out, int n,
                      const int* __restrict__ flag) {
  int i = blockIdx.x * 256 + threadIdx.x;
  if (i >= n) return;
  if (flag[0]) ((float*)out)[i] = in[i];
  else         ((bf16*)out)[i] = __float2bfloat16(in[i]);
}

// ---------------- one-shot weight conversion (all tensors, one dispatch) ----------------
//  [0,1572864)            qkv     [L][768][512]: r<512 -> 0.125*wq[r] (exact, pow2);
//                                 r<640 -> wk[r-512]; else wv[r-640]
//  [1572864,2621440)      wo; [2621440,2719488) rel; [2719488,4816640) pw1;
//  [4816640,4835072)      dw transposed [L][9][512]; [4835072,5883648) pw2;
//  [5883648,10077952)     w1; [10077952,12175104) w2
__global__ void k_w2all(const void* wq, const void* wk, const void* wv, const void* wo,
                        const void* rel, const void* pw1, const void* dwv, const void* pw2,
                        const void* w1, const void* w2,
                        ushort_t* __restrict__ wbf, const int* __restrict__ flag) {
  int f32 = flag[0];
  long i = (long)blockIdx.x * 256 + threadIdx.x;
  if (i >= 12175104L) return;
  float v;
  if (i < 1572864) {
    long l = i / 393216, rem = i - l * 393216;
    int r = (int)(rem >> 9), c = (int)(rem & 511);
    if (r < 512)      v = 0.125f * wload(wq, l * 262144 + (long)r * 512 + c, f32);
    else if (r < 640) v = wload(wk, l * 65536 + (long)(r - 512) * 512 + c, f32);
    else              v = wload(wv, l * 65536 + (long)(r - 640) * 512 + c, f32);
  } else if (i < 2621440) {
    v = wload(wo, i - 1572864, f32);
  } else if (i < 2719488) {
    v = wload(rel, i - 2621440, f32);
  } else if (i < 4816640) {
    v = wload(pw1, i - 2719488, f32);
  } else if (i < 4835072) {
    long r2 = i - 4816640;
    long l = r2 / 4608, rem = r2 - l * 4608;
    int j = (int)(rem >> 9), d = (int)(rem & 511);
    v = wload(dwv, l * 4608 + (long)d * 9 + j, f32);
  } else if (i < 5883648) {
    v = wload(pw2, i - 4835072, f32);
  } else if (i < 10077952) {
    v = wload(w1, i - 5883648, f32);
  } else {
    v = wload(w2, i - 10077952, f32);
  }
  wbf[i] = f2us(v);
}

// ---------------- LayerNorm: wave-shuffle reduce, float2 loads, 2 barriers (r9-proven) -------
__global__ __launch_bounds__(256) void k_ln(const float* __restrict__ x,
    const void* __restrict__ w, const void* __restrict__ bb, long woff,
    float* __restrict__ o, ushort_t* __restrict__ oA, const int* __restrict__ flag) {
  int f32 = flag[0];
  int row = blockIdx.x;
  int t = threadIdx.x;
  int lane = t & 63, wv = t >> 6;
  float2 v = ((const float2*)(x + (long)row * Dc))[t];
  float s = v.x + v.y;
#pragma unroll
  for (int o2 = 1; o2 < 64; o2 <<= 1) s += __shfl_xor(s, o2, 64);
  __shared__ float ws[8];
  if (lane == 0) ws[wv] = s;
  __syncthreads();
  float mean = (ws[0] + ws[1] + ws[2] + ws[3]) * (1.0f / Dc);
  float dx = v.x - mean, dy = v.y - mean;
  float s2 = dx * dx + dy * dy;
#pragma unroll
  for (int o2 = 1; o2 < 64; o2 <<= 1) s2 += __shfl_xor(s2, o2, 64);
  if (lane == 0) ws[4 + wv] = s2;
  __syncthreads();
  float inv = 1.0f / sqrtf((ws[4] + ws[5] + ws[6] + ws[7]) * (1.0f / Dc) + EPSc);
  float v0 = dx * inv * wload(w, woff + 2 * t, f32)     + wload(bb, woff + 2 * t, f32);
  float v1 = dy * inv * wload(w, woff + 2 * t + 1, f32) + wload(bb, woff + 2 * t + 1, f32);
  float2 ov; ov.x = v0; ov.y = v1;
  ((float2*)(o + (long)row * Dc))[t] = ov;
  ((uint_t*)(oA + (long)row * Dc))[t] = (uint_t)f2us(v0) | ((uint_t)f2us(v1) << 16);
}

// ---------------- bf16 MFMA GEMM, 3-stage counted-vmcnt pipeline (T3+T4, depth 3) -----------
// Prologue stages 0..2; per iter: wait vmcnt(2*LPI) (only CURRENT tile's loads drained, two
// tiles stay in flight), raw barrier, compute, barrier, issue stage it+3 into the buffer just
// freed. Tail decays 2*LPI -> LPI -> 0.
template<int BM, int BN, bool OBF>
__global__ __launch_bounds__(256) void k_gemm_b(const ushort_t* __restrict__ A, int lda,
    const ushort_t* __restrict__ W, void* __restrict__ C, int ldc,
    const float* __restrict__ addend, float alpha, int K) {
  constexpr int WGM = BM / 64;
  constexpr int WGN = 4 / WGM;
  constexpr int WN = BN / WGN;
  constexpr int NJ = WN / 16;
  constexpr int LPI = (BM * 8 + BN * 8) / 256;
  __shared__ ushort_t As[3][BM * 64];
  __shared__ ushort_t Ws[3][BN * 64];
  int t = threadIdx.x;
  int m0 = blockIdx.y * BM, n0 = blockIdx.x * BN;
  int lane = t & 63, wv = t >> 6;
  int l15 = lane & 15, quad = lane >> 4;
  int wrow = (WGM == 2) ? (wv >> 1) * 64 : 0;
  int wcol = (WGM == 2) ? (wv & 1) * WN : wv * WN;
  floatx4 acc[4][NJ];
#pragma unroll
  for (int i = 0; i < 4; ++i)
#pragma unroll
    for (int j = 0; j < NJ; ++j) acc[i][j] = 0;
  int NSTG = K >> 6;
  stage_swz(A, lda, m0, 0, As[0], BM * 8, t);
  stage_swz(W, K,  n0, 0, Ws[0], BN * 8, t);
  if (NSTG > 1) {
    stage_swz(A, lda, m0, 64, As[1], BM * 8, t);
    stage_swz(W, K,  n0, 64, Ws[1], BN * 8, t);
  }
  if (NSTG > 2) {
    stage_swz(A, lda, m0, 128, As[2], BM * 8, t);
    stage_swz(W, K,  n0, 128, Ws[2], BN * 8, t);
  }
  int cur = 0;
  for (int it = 0; it < NSTG; ++it) {
    int remain = NSTG - 1 - it;              // stages issued beyond the current one
    if (remain >= 2)      vmwait<2 * LPI>();
    else if (remain == 1) vmwait<LPI>();
    else                  vmwait<0>();
    __builtin_amdgcn_s_barrier();
    __builtin_amdgcn_sched_barrier(0);
    const ushort_t* Asc = As[cur];
    const ushort_t* Wsc = Ws[cur];
#pragma unroll
    for (int half = 0; half < 2; ++half) {
      int sw = ((half * 4 + quad) ^ (l15 & 7)) << 3;
      short8 af[4], bfr[NJ];
#pragma unroll
      for (int i = 0; i < 4; ++i) af[i] = *(short8*)&Asc[(wrow + i * 16 + l15) * 64 + sw];
#pragma unroll
      for (int j = 0; j < NJ; ++j) bfr[j] = *(short8*)&Wsc[(wcol + j * 16 + l15) * 64 + sw];
#pragma unroll
      for (int i = 0; i < 4; ++i)
#pragma unroll
        for (int j = 0; j < NJ; ++j)
          acc[i][j] = __builtin_amdgcn_mfma_f32_16x16x32_bf16(af[i], bfr[j], acc[i][j], 0, 0, 0);
    }
    __builtin_amdgcn_s_barrier();            // all waves done with buf[cur] before restage
    int nstage = it + 3;
    if (nstage < NSTG) {
      stage_swz(A, lda, m0, nstage * 64, As[cur], BM * 8, t);
      stage_swz(W, K,  n0, nstage * 64, Ws[cur], BN * 8, t);
    }
    cur = (cur == 2) ? 0 : cur + 1;
  }
#pragma unroll
  for (int i = 0; i < 4; ++i) {
#pragma unroll
    for (int j = 0; j < NJ; ++j) {
#pragma unroll
      for (int rg = 0; rg < 4; ++rg) {
        int m = m0 + wrow + i * 16 + quad * 4 + rg;
        int n = n0 + wcol + j * 16 + l15;
        float v = alpha * acc[i][j][rg];
        if (addend) v += addend[(long)m * ldc + n];
        if (OBF) ((ushort_t*)C)[(long)m * ldc + n] = f2us(v);
        else     ((float*)C)[(long)m * ldc + n] = v;
      }
    }
  }
}

// ---------------- gated GEMM, 3-stage counted-vmcnt pipeline: C = gate(A@Wa^T, A@Wg^T) ------
// MODE 0 (glu): C = a*sigmoid(g);  MODE 1 (swiglu): C = silu(a)*g.  BM=64, BN=64.
template<int MODE>
__global__ __launch_bounds__(256) void k_gemm_gate(const ushort_t* __restrict__ A, int lda,
    const ushort_t* __restrict__ Wa, const ushort_t* __restrict__ Wg,
    ushort_t* __restrict__ C, int ldc, int K) {
  __shared__ ushort_t As[3][64 * 64];
  __shared__ ushort_t Wsa[3][64 * 64];
  __shared__ ushort_t Wsg[3][64 * 64];
  int t = threadIdx.x;
  int m0 = blockIdx.y * 64, n0 = blockIdx.x * 64;
  int lane = t & 63, wv = t >> 6;
  int l15 = lane & 15, quad = lane >> 4;
  int wcol = wv * 16;
  floatx4 acca[4], accg[4];
#pragma unroll
  for (int i = 0; i < 4; ++i) { acca[i] = 0; accg[i] = 0; }
  int NSTG = K >> 6;
  stage_swz(A, lda, m0, 0, As[0], 512, t);
  stage_swz(Wa, K, n0, 0, Wsa[0], 512, t);
  stage_swz(Wg, K, n0, 0, Wsg[0], 512, t);
  if (NSTG > 1) {
    stage_swz(A, lda, m0, 64, As[1], 512, t);
    stage_swz(Wa, K, n0, 64, Wsa[1], 512, t);
    stage_swz(Wg, K, n0, 64, Wsg[1], 512, t);
  }
  if (NSTG > 2) {
    stage_swz(A, lda, m0, 128, As[2], 512, t);
    stage_swz(Wa, K, n0, 128, Wsa[2], 512, t);
    stage_swz(Wg, K, n0, 128, Wsg[2], 512, t);
  }
  int cur = 0;
  for (int it = 0; it < NSTG; ++it) {
    int remain = NSTG - 1 - it;
    if (remain >= 2)      vmwait<12>();
    else if (remain == 1) vmwait<6>();
    else                  vmwait<0>();
    __builtin_amdgcn_s_barrier();
    __builtin_amdgcn_sched_barrier(0);
    const ushort_t* Asc = As[cur];
    const ushort_t* Wac = Wsa[cur];
    const ushort_t* Wgc = Wsg[cur];
#pragma unroll
    for (int half = 0; half < 2; ++half) {
      int sw = ((half * 4 + quad) ^ (l15 & 7)) << 3;
      short8 af[4], ba, bg;
#pragma unroll
      for (int i = 0; i < 4; ++i) af[i] = *(short8*)&Asc[(i * 16 + l15) * 64 + sw];
      ba = *(short8*)&Wac[(wcol + l15) * 64 + sw];
      bg = *(short8*)&Wgc[(wcol + l15) * 64 + sw];
#pragma unroll
      for (int i = 0; i < 4; ++i) {
        acca[i] = __builtin_amdgcn_mfma_f32_16x16x32_bf16(af[i], ba, acca[i], 0, 0, 0);
        accg[i] = __builtin_amdgcn_mfma_f32_16x16x32_bf16(af[i], bg, accg[i], 0, 0, 0);
      }
    }
    __builtin_amdgcn_s_barrier();
    int nstage = it + 3;
    if (nstage < NSTG) {
      stage_swz(A, lda, m0, nstage * 64, As[cur], 512, t);
      stage_swz(Wa, K, n0, nstage * 64, Wsa[cur], 512, t);
      stage_swz(Wg, K, n0, nstage * 64, Wsg[cur], 512, t);
    }
    cur = (cur == 2) ? 0 : cur + 1;
  }
#pragma unroll
  for (int i = 0; i < 4; ++i) {
#pragma unroll
    for (int rg = 0; rg < 4; ++rg) {
      int m = m0 + i * 16 + quad * 4 + rg;
      int n = n0 + wcol + l15;
      float a = acca[i][rg], g = accg[i][rg];
      float v;
      if (MODE == 0) v = a * (1.0f / (1.0f + __expf(-g)));
      else           v = (a / (1.0f + __expf(-a))) * g;
      C[(long)m * ldc + n] = f2us(v);
    }
  }
}

// ---------------- flash attention, swapped-QK layout + grid split-K (r9-proven form) ---------
// qkv layout: [4096][768] bf16 — q cols 0..511, K cols 512..639 (g*64), V cols 640..767.
__global__ __launch_bounds__(256, 3) void k_attn(const ushort_t* __restrict__ qkv,
    const ushort_t* __restrict__ relL, const int* __restrict__ alen,
    ushort_t* __restrict__ out, char* __restrict__ part) {
  int bx = blockIdx.x;
  int h = blockIdx.y, b = blockIdx.z;
  int len = alen[b];
  int inv, qt, grp;
  if (bx < 16) { inv = 0; qt = bx; grp = 0; }
  else         { inv = 1; qt = (bx - 16) & 15; grp = (bx - 16) >> 4; }
  int q0 = qt * 64;
  if (inv) { if (q0 + 64 <= len) return; }
  else     { if (q0 >= len) return; }
  int nvalid = min(len - q0, 64);
  int g = h >> 2;
  __shared__ __align__(16) ushort_t UQB[8704];
  __shared__ __align__(16) ushort_t Ks[64 * 64];
  __shared__ __align__(16) ushort_t Vt[64 * 72];
  __shared__ __align__(16) ushort_t Ps[64 * 64];
  __shared__ __align__(16) float fML[128];
  ushort_t* Qs = UQB;
  ushort_t* B2t = UQB;
  int t = threadIdx.x;
  int lane = t & 63, w = t >> 6;
  int l15 = lane & 15, quad = lane >> 4;
  int qw = w * 16;
  {
    int qi = t >> 2, du = (t & 3) * 16;
    const ushort_t* src = qkv + ((long)(b * Tc + q0 + qi)) * QSTR + h * 64 + du;
    *(uint4*)&Qs[qi * 72 + du] = *(const uint4*)(src);
    *(uint4*)&Qs[qi * 72 + du + 8] = *(const uint4*)(src + 8);
  }
  const int koB = inv ? -128 : (q0 - 128);
  const int KSTEP = inv ? 4 : 1;
  const int nIt = inv ? ((grp < 2) ? 5 : 4) : 3;
  uint4 kr0, kr1, vr0, vr1;
  int kj = t >> 2, du = (t & 3) * 16, c0 = du >> 3;
  auto LOADKV = [&](int kt2) {
    int ko = koB + kt2 * 64 + kj;
    if (ko >= 0) {
      long basek = ((long)(b * Tc + ko)) * QSTR + 512 + g * 64 + du;
      kr0 = *(const uint4*)(qkv + basek);
      kr1 = *(const uint4*)(qkv + basek + 8);
      vr0 = *(const uint4*)(qkv + basek + 128);
      vr1 = *(const uint4*)(qkv + basek + 136);
    } else {
      uint4 z = {0, 0, 0, 0};
      kr0 = z; kr1 = z; vr0 = z; vr1 = z;
    }
  };
  LOADKV(grp);
  float m_ = NEGB, l_ = 0.f;
  floatx4 acc[4];
#pragma unroll
  for (int j = 0; j < 4; ++j) acc[j] = 0;
  __syncthreads();
  short8 aq0 = *(short8*)&Qs[(qw + l15) * 72 + quad * 8];
  short8 aq1 = *(short8*)&Qs[(qw + l15) * 72 + 32 + quad * 8];
  float rv_lo = 0.f, rv_hi = 0.f;
  if (inv) {
    int er = (l15 == 1) ? 382 : 0;
    short8 be0 = *(const short8*)(relL + (long)er * 64 + quad * 8);
    short8 be1 = *(const short8*)(relL + (long)er * 64 + 32 + quad * 8);
    floatx4 ec = {0.f, 0.f, 0.f, 0.f};
    ec = __builtin_amdgcn_mfma_f32_16x16x32_bf16(be0, aq0, ec, 0, 0, 0);
    ec = __builtin_amdgcn_mfma_f32_16x16x32_bf16(be1, aq1, ec, 0, 0, 0);
    rv_lo = __shfl(ec[0], l15, 64);
    rv_hi = __shfl(ec[1], l15, 64);
  }
  int sw7 = l15 & 7;
  for (int it = 0; it < nIt; ++it) {
    int kt = inv ? (grp + it * KSTEP) : it;
    int ko0 = koB + kt * 64;
    int t0 = q0 - ko0 + 191;
    bool far_hi = (q0 - ko0 - 63) >= 191;
    bool far_lo = (q0 + 63 - ko0) <= -191;
    bool near = !far_hi && !far_lo;
    int cb = min(max(t0 - 63, 0), 255);
    __syncthreads();   // A
    {
      *(uint4*)&Ks[kj * 64 + ((c0 ^ (kj & 7)) << 3)] = kr0;
      *(uint4*)&Ks[kj * 64 + (((c0 + 1) ^ (kj & 7)) << 3)] = kr1;
      uint_t wds[8] = {vr0.x, vr0.y, vr0.z, vr0.w, vr1.x, vr1.y, vr1.z, vr1.w};
#pragma unroll
      for (int u = 0; u < 8; ++u) {
        Vt[(du + 2 * u) * 72 + kj] = (ushort_t)(wds[u] & 0xffff);
        Vt[(du + 2 * u + 1) * 72 + kj] = (ushort_t)(wds[u] >> 16);
      }
    }
    if (near) {
      __builtin_amdgcn_s_setprio(1);
#pragma unroll
      for (int p = 0; p < 2; ++p) {
        short8 rw0[4], rw1[4];
#pragma unroll
        for (int j = 0; j < 4; ++j) {
          long wr = cb + (p * 4 + j) * 16 + l15;
          rw0[j] = *(const short8*)(relL + wr * 64 + quad * 8);
          rw1[j] = *(const short8*)(relL + wr * 64 + 32 + quad * 8);
        }
#pragma unroll
        for (int j = 0; j < 4; ++j) {
          floatx4 z = {0.f, 0.f, 0.f, 0.f};
          z = __builtin_amdgcn_mfma_f32_16x16x32_bf16(rw0[j], aq0, z, 0, 0, 0);
          z = __builtin_amdgcn_mfma_f32_16x16x32_bf16(rw1[j], aq1, z, 0, 0, 0);
#pragma unroll
          for (int rg = 0; rg < 4; ++rg) {
            int cpr = (p * 4 + j) * 16 + quad * 4 + rg;
            B2t[cpr * 68 + qw + l15] = f2us(z[rg]);
          }
        }
      }
      __builtin_amdgcn_s_setprio(0);
    }
    __syncthreads();   // B
    if (it + 1 < nIt) LOADKV(kt + KSTEP);
    floatx4 s[4];
    __builtin_amdgcn_s_setprio(1);
#pragma unroll
    for (int nt = 0; nt < 4; ++nt) {
      short8 ak0 = *(short8*)&Ks[(nt * 16 + l15) * 64 + ((quad ^ sw7) << 3)];
      short8 ak1 = *(short8*)&Ks[(nt * 16 + l15) * 64 + (((4 + quad) ^ sw7) << 3)];
      floatx4 z = {0.f, 0.f, 0.f, 0.f};
      z = __builtin_amdgcn_mfma_f32_16x16x32_bf16(ak0, aq0, z, 0, 0, 0);
      z = __builtin_amdgcn_mfma_f32_16x16x32_bf16(ak1, aq1, z, 0, 0, 0);
      s[nt] = z;
    }
    __builtin_amdgcn_s_setprio(0);
    if (near) {
#pragma unroll
      for (int nt = 0; nt < 4; ++nt)
#pragma unroll
        for (int rg = 0; rg < 4; ++rg) {
          int c = t0 + qw + l15 - (nt * 16 + quad * 4 + rg);
          c = min(max(c, 0), 382);
          s[nt][rg] += us2f(B2t[(c - cb) * 68 + qw + l15]);
        }
    } else {
      float rv = far_hi ? rv_hi : rv_lo;
#pragma unroll
      for (int nt = 0; nt < 4; ++nt)
#pragma unroll
        for (int rg = 0; rg < 4; ++rg) s[nt][rg] += rv;
    }
    if (!inv) {
#pragma unroll
      for (int nt = 0; nt < 4; ++nt)
#pragma unroll
        for (int rg = 0; rg < 4; ++rg) {
          int ko = ko0 + nt * 16 + quad * 4 + rg;
          if (ko >= len) s[nt][rg] = NEGB;
        }
    }
    float mx = s[0][0];
#pragma unroll
    for (int nt = 0; nt < 4; ++nt)
#pragma unroll
      for (int rg = 0; rg < 4; ++rg) mx = fmaxf(mx, s[nt][rg]);
    mx = fmaxf(mx, __shfl_xor(mx, 16, 64));
    mx = fmaxf(mx, __shfl_xor(mx, 32, 64));
    float mn = fmaxf(m_, mx);
    float al = __expf(m_ - mn);
    float ps = 0.f;
#pragma unroll
    for (int nt = 0; nt < 4; ++nt)
#pragma unroll
      for (int rg = 0; rg < 4; ++rg) {
        float p = __expf(s[nt][rg] - mn);
        s[nt][rg] = p;
        ps += p;
      }
    ps += __shfl_xor(ps, 16, 64);
    ps += __shfl_xor(ps, 32, 64);
    l_ = l_ * al + ps;
    m_ = mn;
    if (quad == 0) fML[qw + l15] = al;
#pragma unroll
    for (int nt = 0; nt < 4; ++nt)
#pragma unroll
      for (int pr = 0; pr < 2; ++pr) {
        uint_t pk = (uint_t)f2us(s[nt][2 * pr]) | ((uint_t)f2us(s[nt][2 * pr + 1]) << 16);
        int e = nt * 16 + quad * 4 + pr * 2;
        *(uint_t*)&Ps[(qw + l15) * 64 + (((e >> 3) ^ sw7) << 3) + (e & 7)] = pk;
      }
    floatx4 av = *(floatx4*)&fML[qw + quad * 4];
#pragma unroll
    for (int j = 0; j < 4; ++j)
#pragma unroll
      for (int rg = 0; rg < 4; ++rg) acc[j][rg] *= av[rg];
    short8 ap0 = *(short8*)&Ps[(qw + l15) * 64 + ((quad ^ sw7) << 3)];
    short8 ap1 = *(short8*)&Ps[(qw + l15) * 64 + (((4 + quad) ^ sw7) << 3)];
    __builtin_amdgcn_s_setprio(1);
#pragma unroll
    for (int j = 0; j < 4; ++j) {
      short8 bv0 = *(short8*)&Vt[(j * 16 + l15) * 72 + quad * 8];
      short8 bv1 = *(short8*)&Vt[(j * 16 + l15) * 72 + 32 + quad * 8];
      acc[j] = __builtin_amdgcn_mfma_f32_16x16x32_bf16(ap0, bv0, acc[j], 0, 0, 0);
      acc[j] = __builtin_amdgcn_mfma_f32_16x16x32_bf16(ap1, bv1, acc[j], 0, 0, 0);
    }
    __builtin_amdgcn_s_setprio(0);
  }
  if (inv) {
    char* pp = part + (long)((((b * 8 + h) * 16 + qt) * 4 + grp)) * PSTRIDE;
    ushort_t* Cp = (ushort_t*)pp;
    float* mp = (float*)(pp + 8192);
#pragma unroll
    for (int j = 0; j < 4; ++j)
#pragma unroll
      for (int rg = 0; rg < 4; ++rg)
        Cp[(qw + quad * 4 + rg) * 64 + j * 16 + l15] = f2us(acc[j][rg]);
    if (quad == 0) { mp[qw + l15] = m_; mp[64 + qw + l15] = l_; }
  } else {
    if (quad == 0) fML[64 + qw + l15] = l_;
    floatx4 lv = *(floatx4*)&fML[64 + qw + quad * 4];
#pragma unroll
    for (int rg = 0; rg < 4; ++rg) {
      int R = qw + quad * 4 + rg;
      if (R < nvalid) {
        float invL = 1.0f / lv[rg];
#pragma unroll
        for (int j = 0; j < 4; ++j)
          out[((long)(b * Tc + q0 + R)) * Dc + h * 64 + j * 16 + l15] = f2us(acc[j][rg] * invL);
      }
    }
  }
}

// ---------------- exact split-K combine for inv partials ----------------
__global__ __launch_bounds__(256) void k_comb(const char* __restrict__ part,
    const int* __restrict__ alen, ushort_t* __restrict__ out) {
  int qt = blockIdx.x, h = blockIdx.y, b = blockIdx.z;
  int len = alen[b];
  int q0 = qt * 64;
  if (q0 + 64 <= len) return;
  int nskip = max(len - q0, 0);
  int t = threadIdx.x;
  int d = t & 63, r0 = (t >> 6) * 16;
  const char* pb = part + (long)(((b * 8 + h) * 16 + qt) * 4) * PSTRIDE;
#pragma unroll 4
  for (int i = 0; i < 16; ++i) {
    int r = r0 + i;
    if (r < nskip) continue;
    float mg[4], lg[4], M = NEGB;
#pragma unroll
    for (int g2 = 0; g2 < 4; ++g2) {
      const float* mp = (const float*)(pb + g2 * PSTRIDE + 8192);
      mg[g2] = mp[r];
      lg[g2] = mp[64 + r];
      M = fmaxf(M, mg[g2]);
    }
    float L = 0.f, wgt[4];
#pragma unroll
    for (int g2 = 0; g2 < 4; ++g2) { wgt[g2] = __expf(mg[g2] - M); L += lg[g2] * wgt[g2]; }
    float v = 0.f;
#pragma unroll
    for (int g2 = 0; g2 < 4; ++g2)
      v += us2f(((const ushort_t*)(pb + g2 * PSTRIDE))[r * 64 + d]) * wgt[g2];
    out[((long)(b * Tc + q0 + r)) * Dc + h * 64 + d] = f2us(v / L);
  }
}

// ---------------- depthwise conv (gated input [4096][512], short8) ----------------
__global__ void k_dwconv(const ushort_t* __restrict__ in, const ushort_t* __restrict__ dwT,
                         ushort_t* __restrict__ out, int n8) {
  int i = blockIdx.x * 256 + threadIdx.x;
  if (i >= n8) return;
  int row = i >> 6;            // 0..4095
  int d8 = (i & 63) << 3;
  int t = row & (Tc - 1);
  int b = row >> 10;
  float acc[8] = {0, 0, 0, 0, 0, 0, 0, 0};
#pragma unroll
  for (int j = 0; j < 9; ++j) {
    int tt = t + j - 4;
    if (tt < 0 || tt >= Tc) continue;
    short8 vv = *(const short8*)&in[((long)(b * Tc + tt) << 9) + d8];
    short8 dv = *(const short8*)&dwT[j * 512 + d8];
#pragma unroll
    for (int e = 0; e < 8; ++e)
      acc[e] += us2f((ushort_t)vv[e]) * us2f((ushort_t)dv[e]);
  }
  short8 o8;
#pragma unroll
  for (int e = 0; e < 8; ++e)
    o8[e] = (short)f2us(acc[e] * (1.0f / (1.0f + __expf(-acc[e]))));
  *(short8*)&out[(long)row * 512 + d8] = o8;
}

extern "C" void kernel_launch(void* const* d_in, const int* in_sizes, int n_in,
                              void* d_out, int out_size, void* d_ws, size_t ws_size,
                              hipStream_t stream) {
  const void* x_in = d_in[0];
  const int*  alen = (const int*)d_in[1];
  const void* ln1w = d_in[2];
  const void* ln1b = d_in[3];
  const void* wq   = d_in[4];
  const void* wk   = d_in[5];
  const void* wv   = d_in[6];
  const void* wo   = d_in[7];
  const void* rel  = d_in[8];
  const void* ln2w = d_in[9];
  const void* ln2b = d_in[10];
  const void* pw1  = d_in[11];
  const void* dwv  = d_in[12];
  const void* pw2  = d_in[13];
  const void* ln3w = d_in[14];
  const void* ln3b = d_in[15];
  const void* w1   = d_in[16];
  const void* w2   = d_in[17];

  // ---- workspace layout (bytes) ----
  char* base = (char*)d_ws;
  int*      flag = (int*)base;                       // 256
  float*    xf   = (float*)(base + 256);             // 8 MB f32 residual
  float*    lnb  = (float*)(base + 256 + 8388608);   // 8 MB f32 LN out (addend)
  ushort_t* lnA  = (ushort_t*)(base + 16777472);     // 4 MB bf16 LN out (GEMM A)
  ushort_t* wbf  = (ushort_t*)(base + 20971776);     // bf16 weights
  char*     U    = base + 45321984;                  // phase union
  // attn phase
  ushort_t* qkv = (ushort_t*)U;                      // 6 MB fused q|K|V [4096][768]
  ushort_t* ab  = (ushort_t*)(U + 6291456);          // 4 MB
  char*     partA = U + 10485760;                    // 17.8 MB attn partials
  // conv/ffn phase
  ushort_t* big = (ushort_t*)U;                      // up to 8 MB (gated outputs)
  ushort_t* cb  = (ushort_t*)(U + 16777216);         // 4 MB
  size_t REQ = 45321984 + 16777216 + 4194304;
  size_t REQ2 = 45321984 + 35651584;
  if (REQ2 > REQ) REQ = REQ2;
  if (ws_size < REQ) return;

  // bf16 weight table offsets (elements)
  ushort_t* qkvB  = wbf + 0;         // [L][768][512] (wq pre-scaled by 0.125)
  ushort_t* woB   = wbf + 1572864;
  ushort_t* relB  = wbf + 2621440;
  ushort_t* pw1B  = wbf + 2719488;
  ushort_t* dwB   = wbf + 4816640;   // [L][9][512] transposed
  ushort_t* pw2B  = wbf + 4835072;
  ushort_t* w1B   = wbf + 5883648;
  ushort_t* w2B   = wbf + 10077952;

  k_detect<<<1, 256, 0, stream>>>(x_in, flag);
  k_in<<<(int)((NE + 255) / 256), 256, 0, stream>>>(x_in, xf, (int)NE, flag);
  k_w2all<<<47559, 256, 0, stream>>>(wq, wk, wv, wo, rel, pw1, dwv, pw2, w1, w2, wbf, flag);

  for (int i = 0; i < 4; ++i) {
    long oLN = (long)i * Dc;
    // ---- attention ----
    k_ln<<<NBT, 256, 0, stream>>>(xf, ln1w, ln1b, oLN, lnb, lnA, flag);
    k_gemm_b<64, 64, true><<<dim3(12, 64), 256, 0, stream>>>(lnA, Dc, qkvB + (long)i * 393216, qkv, QSTR, nullptr, 1.0f, 512);
    k_attn<<<dim3(80, 8, 4), 256, 0, stream>>>(qkv, relB + (long)i * 24512, alen, ab, partA);
    k_comb<<<dim3(16, 8, 4), 256, 0, stream>>>(partA, alen, ab);
    k_gemm_b<64, 64, false><<<dim3(8, 64), 256, 0, stream>>>(ab, Dc, woB + (long)i * 262144, xf, Dc, lnb, 1.0f, 512);

    // ---- conv ----
    k_ln<<<NBT, 256, 0, stream>>>(xf, ln2w, ln2b, oLN, lnb, lnA, flag);
    k_gemm_gate<0><<<dim3(8, 64), 256, 0, stream>>>(lnA, Dc, pw1B + (long)i * 524288,
        pw1B + (long)i * 524288 + 262144, big, 512, 512);
    k_dwconv<<<NBT * 512 / 8 / 256, 256, 0, stream>>>(big, dwB + (long)i * 4608, cb, NBT * 512 / 8);
    k_gemm_b<64, 64, false><<<dim3(8, 64), 256, 0, stream>>>(cb, Dc, pw2B + (long)i * 262144, xf, Dc, lnb, 1.0f, 512);

    // ---- ffn ----
    k_ln<<<NBT, 256, 0, stream>>>(xf, ln3w, ln3b, oLN, lnb, lnA, flag);
    k_gemm_gate<1><<<dim3(16, 64), 256, 0, stream>>>(lnA, Dc, w1B + (long)i * 1048576,
        w1B + (long)i * 1048576 + 524288, big, 1024, 512);
    k_gemm_b<64, 64, false><<<dim3(8, 64), 256, 0, stream>>>(big, 1024, w2B + (long)i * 524288, xf, Dc, lnb, 1.0f, 1024);
  }

  k_out<<<(int)((NE + 255) / 256), 256, 0, stream>>>(xf, d_out, (int)NE, flag);
}